// Round 11
// baseline (206.695 us; speedup 1.0000x reference)
//
#include <hip/hip_runtime.h>

#define BSZ 8
#define LSEQ 8192
#define DDIM 256
#define CHUNK 16
#define WARM 32
#define STEPS (CHUNK + WARM)   // 48
#define CPB 16                 // chains per block

typedef float f32x4 __attribute__((ext_vector_type(4)));
typedef _Float16 h8 __attribute__((ext_vector_type(8)));
typedef _Float16 h4 __attribute__((ext_vector_type(4)));
typedef _Float16 h2 __attribute__((ext_vector_type(2)));

// U layout (R4-proven): row-major rows, cols swizzled within each 64-block:
//   U[row*256 + g64*64 + l15*4 + ct] == logical U[row][g64*64 + ct*16 + l15]
//
// Cross-round lessons enforced:
//  - R4/R8/R10: scan sweet spot = 8 waves x 32 cols, CHUNK=16, 1 block/CU.
//    The R4 kernel (55.5-58us measured) is FROZEN verbatim below.
//  - R9/R10: gemm_u was occupancy-starved in every round (>=67KB LDS -> 2
//    blocks/CU -> 25% cap) and latency-bound (all pipes <8%). This round:
//    16.9KB LDS, 2048 blocks, ~5 blocks/CU -> hide staging latency with TLP.
//  - R4-R9: allocator clamps ~100 VGPR; keep live sets small (one bf[8]=32
//    regs at a time; acc[2][4]=32; static indices only — rule #20).

// ---------------- U = x @ B^T (+ folded matrix conversions) ----------------
// 2048 blocks x 32 rows, 256 threads (4 waves). x staged once to LDS fp16
// (shared af); each wave owns a 64-col group; B read fp32 from L2 per-ct and
// converted in-register. High occupancy does the latency hiding.
__global__ __launch_bounds__(256) void k_gemm_u(
    const float* __restrict__ x, const float* __restrict__ A,
    const float* __restrict__ B, const float* __restrict__ C,
    _Float16* __restrict__ U, _Float16* __restrict__ AhT,
    _Float16* __restrict__ Ch, _Float16* __restrict__ Zph) {
  __shared__ __align__(16) _Float16 xh[32][264];  // 16.9 KB -> 9 blocks/CU by LDS
  const int tid = threadIdx.x, wv = tid >> 6, lane = tid & 63;
  const int l15 = lane & 15, q = lane >> 4;

  if (blockIdx.x < 256) {  // side duty: operand conversions for the scan
    const int r = blockIdx.x;
    AhT[tid * 256 + r] = (_Float16)A[r * 256 + tid];   // AhT[n][k] = A[k][n]
    Ch[r * 256 + tid] = (_Float16)C[r * 256 + tid];    // Ch[n][k]  = C[n][k]
    if (r == 0) { Zph[tid] = (_Float16)0.f; Zph[tid + 256] = (_Float16)0.f; }
  }

  const size_t rowbase = (size_t)blockIdx.x * 32;
#pragma unroll
  for (int i = 0; i < 8; ++i) {  // 2048 float4 = 32 rows x 64 float4/row
    const int f4 = i * 256 + tid;
    const int row = f4 >> 6, c4 = f4 & 63;
    float4 v = *(const float4*)(x + (rowbase + row) * 256 + c4 * 4);
    h4 h;
    h[0] = (_Float16)v.x; h[1] = (_Float16)v.y; h[2] = (_Float16)v.z; h[3] = (_Float16)v.w;
    *(h4*)&xh[row][c4 * 4] = h;
  }
  __syncthreads();

  f32x4 acc[2][4] = {};  // [rt][ct] — fully static indexing (rule #20)
#pragma unroll
  for (int ct = 0; ct < 4; ++ct) {
    const int n = wv * 64 + ct * 16 + l15;  // this lane's B^T column
    h8 bf[8];  // one 32-reg live set at a time (under the ~100-VGPR clamp)
#pragma unroll
    for (int kb = 0; kb < 8; ++kb) {
      const float* bp = B + (size_t)n * 256 + kb * 32 + q * 8;
      float4 b0 = *(const float4*)bp, b1 = *(const float4*)(bp + 4);
      h8 f;
      f[0] = (_Float16)b0.x; f[1] = (_Float16)b0.y; f[2] = (_Float16)b0.z; f[3] = (_Float16)b0.w;
      f[4] = (_Float16)b1.x; f[5] = (_Float16)b1.y; f[6] = (_Float16)b1.z; f[7] = (_Float16)b1.w;
      bf[kb] = f;
    }
#pragma unroll
    for (int rt = 0; rt < 2; ++rt)
#pragma unroll
      for (int kb = 0; kb < 8; ++kb) {
        h8 af = *(const h8*)&xh[rt * 16 + l15][kb * 32 + q * 8];
        acc[rt][ct] = __builtin_amdgcn_mfma_f32_16x16x32_f16(af, bf[kb], acc[rt][ct], 0, 0, 0);
      }
  }
#pragma unroll
  for (int rt = 0; rt < 2; ++rt) {
    const size_t grow = rowbase + rt * 16 + q * 4;
#pragma unroll
    for (int r = 0; r < 4; ++r) {
      h4 hv;
      hv[0] = (_Float16)acc[rt][0][r]; hv[1] = (_Float16)acc[rt][1][r];
      hv[2] = (_Float16)acc[rt][2][r]; hv[3] = (_Float16)acc[rt][3][r];
      *(h4*)(U + (grow + r) * 256 + wv * 64 + l15 * 4) = hv;  // swizzled layout
    }
  }
}

// ---------------- fused MFMA scan + out-projection (R4 kernel, verbatim) ----
// 256 blocks / CHUNK=16 / 1 block/CU; 8 waves x 32 cols (64KB LDS af/step).
// Measured 55.5-58us across R4/R10. No changes.
__global__ __launch_bounds__(512, 2) void k_scan(const _Float16* __restrict__ U,
                                                 const _Float16* __restrict__ AhT,
                                                 const _Float16* __restrict__ Ch,
                                                 const _Float16* __restrict__ Zp,
                                                 float* __restrict__ O) {
  __shared__ __align__(16) _Float16 st[2][CPB][264];  // state dbuf, proven layout
  const int tid = threadIdx.x, wv = tid >> 6, lane = tid & 63;
  const int l15 = lane & 15, q = lane >> 4;
  const int g64 = wv >> 1, hf = wv & 1;   // wave owns cols g64*64 + (2hf+ctl)*16 + l15
  const int b = blockIdx.x >> 5;
  const int c0 = (blockIdx.x & 31) * CPB;
  const size_t bbase = (size_t)b * LSEQ;

  h8 bf[2][8], cf[2][8];
#pragma unroll
  for (int ctl = 0; ctl < 2; ++ctl)
#pragma unroll
    for (int kb = 0; kb < 8; ++kb) {
      const size_t mo = (size_t)(g64 * 64 + (2 * hf + ctl) * 16 + l15) * 256 + kb * 32 + q * 8;
      bf[ctl][kb] = *(const h8*)(AhT + mo);
      cf[ctl][kb] = *(const h8*)(Ch + mo);
    }

  for (int i = tid; i < CPB * 264; i += 512) ((_Float16*)st[0])[i] = (_Float16)0.f;

  // per-lane U fragment load (2 ct-values, 4B) for chain q*4+r at local time t
  auto uload = [&](int t, int r) -> h2 {
    const int lr = (c0 + q * 4 + r) * CHUNK + t;
    const _Float16* p = (lr < 0 || lr >= LSEQ)
                            ? (Zp + l15 * 4 + 2 * hf)
                            : (U + (bbase + (size_t)lr) * 256 + g64 * 64 + l15 * 4 + 2 * hf);
    return *(const h2*)p;
  };

  // O running pointers: col base for ctl=0; ctl=1 is +16 floats
  float* op[4];
#pragma unroll
  for (int r = 0; r < 4; ++r)
    op[r] = O + (bbase + (size_t)(c0 + q * 4 + r) * CHUNK) * 256 + g64 * 64 + 2 * hf * 16 + l15;

  h2 up0 = uload(-WARM, 0), up1 = uload(-WARM, 1), up2 = uload(-WARM, 2), up3 = uload(-WARM, 3);
  __syncthreads();  // one full drain: zero-init + frag loads

  int cb = 0;
#pragma unroll 1
  for (int g = 0; g <= STEPS; ++g) {
    const int t = g - WARM;  // computes S_t (g<STEPS); emits O_{t-1} (t>=1)
    // prefetch next step's U fragments (overlaps this step's MFMA; never drained)
    h2 un0 = uload(t + 1, 0), un1 = uload(t + 1, 1), un2 = uload(t + 1, 2), un3 = uload(t + 1, 3);
    if (g < STEPS) {
      f32x4 acc[2];
#pragma unroll
      for (int ctl = 0; ctl < 2; ++ctl) {
        acc[ctl][0] = (float)up0[ctl]; acc[ctl][1] = (float)up1[ctl];
        acc[ctl][2] = (float)up2[ctl]; acc[ctl][3] = (float)up3[ctl];
      }
      if (t >= 1) {
        f32x4 acc2[2] = {};
#pragma unroll
        for (int kb = 0; kb < 8; ++kb) {
          h8 af = *(const h8*)&st[cb][l15][kb * 32 + q * 8];
#pragma unroll
          for (int ctl = 0; ctl < 2; ++ctl)
            acc[ctl] = __builtin_amdgcn_mfma_f32_16x16x32_f16(af, bf[ctl][kb], acc[ctl], 0, 0, 0);
#pragma unroll
          for (int ctl = 0; ctl < 2; ++ctl)
            acc2[ctl] = __builtin_amdgcn_mfma_f32_16x16x32_f16(af, cf[ctl][kb], acc2[ctl], 0, 0, 0);
        }
#pragma unroll
        for (int ctl = 0; ctl < 2; ++ctl)
#pragma unroll
          for (int r = 0; r < 4; ++r)
            st[cb ^ 1][q * 4 + r][g64 * 64 + (2 * hf + ctl) * 16 + l15] = (_Float16)acc[ctl][r];
#pragma unroll
        for (int r = 0; r < 4; ++r) {
          op[r][0] = acc2[0][r];
          op[r][16] = acc2[1][r];
          op[r] += 256;
        }
      } else {
#pragma unroll
        for (int kb = 0; kb < 8; ++kb) {
          h8 af = *(const h8*)&st[cb][l15][kb * 32 + q * 8];
#pragma unroll
          for (int ctl = 0; ctl < 2; ++ctl)
            acc[ctl] = __builtin_amdgcn_mfma_f32_16x16x32_f16(af, bf[ctl][kb], acc[ctl], 0, 0, 0);
        }
#pragma unroll
        for (int ctl = 0; ctl < 2; ++ctl)
#pragma unroll
          for (int r = 0; r < 4; ++r)
            st[cb ^ 1][q * 4 + r][g64 * 64 + (2 * hf + ctl) * 16 + l15] = (_Float16)acc[ctl][r];
      }
    } else {  // g == STEPS: final O_{CHUNK-1} only
      f32x4 acc2[2] = {};
#pragma unroll
      for (int kb = 0; kb < 8; ++kb) {
        h8 af = *(const h8*)&st[cb][l15][kb * 32 + q * 8];
#pragma unroll
        for (int ctl = 0; ctl < 2; ++ctl)
          acc2[ctl] = __builtin_amdgcn_mfma_f32_16x16x32_f16(af, cf[ctl][kb], acc2[ctl], 0, 0, 0);
      }
#pragma unroll
      for (int r = 0; r < 4; ++r) {
        op[r][0] = acc2[0][r];
        op[r][16] = acc2[1][r];
      }
    }
    // cross-wave hazard is LDS-only (st dbuf): wait LDS, barrier — NO vmem drain
    asm volatile("s_waitcnt lgkmcnt(0)" ::: "memory");
    __builtin_amdgcn_s_barrier();
    asm volatile("" ::: "memory");
    up0 = un0; up1 = un1; up2 = un2; up3 = un3;
    cb ^= 1;
  }
}

extern "C" void kernel_launch(void* const* d_in, const int* in_sizes, int n_in,
                              void* d_out, int out_size, void* d_ws, size_t ws_size,
                              hipStream_t stream) {
  const float* x = (const float*)d_in[0];
  const float* A = (const float*)d_in[1];
  const float* B = (const float*)d_in[2];
  const float* C = (const float*)d_in[3];

  char* ws = (char*)d_ws;
  _Float16* U = (_Float16*)ws;                            // 33.5 MB (swizzled)
  _Float16* AhT = (_Float16*)(ws + 33554432);             // 128 KB
  _Float16* Ch = (_Float16*)(ws + 33554432 + 131072);     // 128 KB
  _Float16* Zph = (_Float16*)(ws + 33554432 + 262144);    // 1 KB zeros
  float* out = (float*)d_out;

  hipLaunchKernelGGL(k_gemm_u, dim3(2048), dim3(256), 0, stream, x, A, B, C, U, AhT,
                     Ch, Zph);
  hipLaunchKernelGGL(k_scan, dim3(256), dim3(512), 0, stream, U, AhT, Ch, Zph, out);
}

// Round 13
// 168.105 us; speedup vs baseline: 1.2296x; 1.2296x over previous
//
#include <hip/hip_runtime.h>

#define BSZ 8
#define LSEQ 8192
#define DDIM 256
#define CHUNK 16
#define WARM 32
#define STEPS (CHUNK + WARM)   // 48
#define CPB 16                 // chains per block

typedef float f32x4 __attribute__((ext_vector_type(4)));
typedef _Float16 h8 __attribute__((ext_vector_type(8)));
typedef _Float16 h4 __attribute__((ext_vector_type(4)));
typedef _Float16 h2 __attribute__((ext_vector_type(2)));

// U layout (R4-proven): row-major rows, cols swizzled within each 64-block:
//   U[row*256 + g64*64 + l15*4 + ct] == logical U[row][g64*64 + ct*16 + l15]
//
// Cross-round lessons enforced:
//  - R4/R8/R10: scan sweet spot = 8 waves x 32 cols, CHUNK=16, 1 block/CU;
//    kernel FROZEN verbatim (55.5-58us measured).
//  - R11: per-lane B-column loads = 16-line divergent wave-loads; B re-read
//    256KB/block -> TA-issue bound at 0.94 TB/s. Fix: Bpack fragment-major so
//    every bf[kb] wave-load is 1KB CONTIGUOUS (8 fully-consumed lines).
//  - R4-R9: ~100-VGPR clamp -> no long-lived operand register sets: bf is a
//    32-reg transient reloaded per ct (by construction, nothing to sink).
//  - Launch-count is a non-lever (~71us fixed overhead at 2 AND 3 launches).
// (R12 bench was an infra failure — container acquire — this source is the
//  R11-fix resubmitted after an index-contract re-audit.)

// ---------------- pack kernel: Bpack fragment-major + scan operands ----------
// Bpack flat index for (ct_g, kb, lane=q*16+l15, j):
//   ((ct_g*8 + kb)*64 + lane)*8 + j   holds  Bt[kb*32+q*8+j][ct_g*16+l15]
// i.e. exactly lane's h8 B-fragment -> gemm bf load = 1KB contiguous per wave.
__global__ void k_pack(const float* __restrict__ A, const float* __restrict__ B,
                       const float* __restrict__ C, _Float16* __restrict__ AhT,
                       _Float16* __restrict__ Ch, _Float16* __restrict__ Zph,
                       _Float16* __restrict__ Bpack) {
  const int n = blockIdx.x, k = threadIdx.x;
  AhT[k * 256 + n] = (_Float16)A[n * 256 + k];   // AhT[c][r]=A[r][c] (r=n here)
  Ch[n * 256 + k] = (_Float16)C[n * 256 + k];    // Ch[n][k] = C[n][k]
  if (n == 0) { Zph[k] = (_Float16)0.f; Zph[k + 256] = (_Float16)0.f; }
  // Bt[k][n] = B[n][k]
  const int ctg = n >> 4, l15 = n & 15, kb = k >> 5, q = (k >> 3) & 3, j = k & 7;
  Bpack[(((ctg * 8 + kb) * 64) + q * 16 + l15) * 8 + j] = (_Float16)B[n * 256 + k];
}

// ---------------- U = x @ B^T ----------------
// 2048 blocks x 32 rows, 256 threads (4 waves), 16.9KB LDS -> high occupancy.
// Wave wv owns cols wv*64..+63 (4 ct-groups). Per ct: bf[8] loaded as 8
// COALESCED 1KB wave-loads from Bpack (L2-hot); af from LDS; acc[2][4] static.
__global__ __launch_bounds__(256) void k_gemm_u(const float* __restrict__ x,
                                                const _Float16* __restrict__ Bpack,
                                                _Float16* __restrict__ U) {
  __shared__ __align__(16) _Float16 xh[32][264];  // 16.9 KB
  const int tid = threadIdx.x, wv = tid >> 6, lane = tid & 63;
  const int l15 = lane & 15, q = lane >> 4;

  const size_t rowbase = (size_t)blockIdx.x * 32;
#pragma unroll
  for (int i = 0; i < 8; ++i) {  // 2048 float4 = 32 rows x 64 float4/row
    const int f4 = i * 256 + tid;
    const int row = f4 >> 6, c4 = f4 & 63;
    float4 v = *(const float4*)(x + (rowbase + row) * 256 + c4 * 4);
    h4 h;
    h[0] = (_Float16)v.x; h[1] = (_Float16)v.y; h[2] = (_Float16)v.z; h[3] = (_Float16)v.w;
    *(h4*)&xh[row][c4 * 4] = h;
  }
  __syncthreads();

  f32x4 acc[2][4] = {};  // [rt][ctl] — fully static indexing (rule #20)
#pragma unroll 1
  for (int ctl = 0; ctl < 4; ++ctl) {
    // this wave's ct-group = wv*4 + ctl; fragment base is lane-contiguous
    const _Float16* bp = Bpack + (((size_t)(wv * 4 + ctl) * 8) * 64 + lane) * 8;
    h8 bf[8];  // 32-reg transient, loaded per-ct (nothing loop-invariant)
#pragma unroll
    for (int kb = 0; kb < 8; ++kb)
      bf[kb] = *(const h8*)(bp + (size_t)kb * 64 * 8);  // 1KB coalesced/wave
#pragma unroll
    for (int rt = 0; rt < 2; ++rt)
#pragma unroll
      for (int kb = 0; kb < 8; ++kb) {
        h8 af = *(const h8*)&xh[rt * 16 + l15][kb * 32 + q * 8];
        acc[rt][ctl] = __builtin_amdgcn_mfma_f32_16x16x32_f16(af, bf[kb], acc[rt][ctl], 0, 0, 0);
      }
  }
#pragma unroll
  for (int rt = 0; rt < 2; ++rt) {
    const size_t grow = rowbase + rt * 16 + q * 4;
#pragma unroll
    for (int r = 0; r < 4; ++r) {
      h4 hv;
      hv[0] = (_Float16)acc[rt][0][r]; hv[1] = (_Float16)acc[rt][1][r];
      hv[2] = (_Float16)acc[rt][2][r]; hv[3] = (_Float16)acc[rt][3][r];
      *(h4*)(U + (grow + r) * 256 + wv * 64 + l15 * 4) = hv;  // swizzled layout
    }
  }
}

// ---------------- fused MFMA scan + out-projection (frozen, R4/R10) ----------
// 256 blocks / CHUNK=16 / 1 block/CU; 8 waves x 32 cols. Measured 55.5-58us.
__global__ __launch_bounds__(512, 2) void k_scan(const _Float16* __restrict__ U,
                                                 const _Float16* __restrict__ AhT,
                                                 const _Float16* __restrict__ Ch,
                                                 const _Float16* __restrict__ Zp,
                                                 float* __restrict__ O) {
  __shared__ __align__(16) _Float16 st[2][CPB][264];  // state dbuf, proven layout
  const int tid = threadIdx.x, wv = tid >> 6, lane = tid & 63;
  const int l15 = lane & 15, q = lane >> 4;
  const int g64 = wv >> 1, hf = wv & 1;   // wave owns cols g64*64 + (2hf+ctl)*16 + l15
  const int b = blockIdx.x >> 5;
  const int c0 = (blockIdx.x & 31) * CPB;
  const size_t bbase = (size_t)b * LSEQ;

  h8 bf[2][8], cf[2][8];
#pragma unroll
  for (int ctl = 0; ctl < 2; ++ctl)
#pragma unroll
    for (int kb = 0; kb < 8; ++kb) {
      const size_t mo = (size_t)(g64 * 64 + (2 * hf + ctl) * 16 + l15) * 256 + kb * 32 + q * 8;
      bf[ctl][kb] = *(const h8*)(AhT + mo);
      cf[ctl][kb] = *(const h8*)(Ch + mo);
    }

  for (int i = tid; i < CPB * 264; i += 512) ((_Float16*)st[0])[i] = (_Float16)0.f;

  // per-lane U fragment load (2 ct-values, 4B) for chain q*4+r at local time t
  auto uload = [&](int t, int r) -> h2 {
    const int lr = (c0 + q * 4 + r) * CHUNK + t;
    const _Float16* p = (lr < 0 || lr >= LSEQ)
                            ? (Zp + l15 * 4 + 2 * hf)
                            : (U + (bbase + (size_t)lr) * 256 + g64 * 64 + l15 * 4 + 2 * hf);
    return *(const h2*)p;
  };

  // O running pointers: col base for ctl=0; ctl=1 is +16 floats
  float* op[4];
#pragma unroll
  for (int r = 0; r < 4; ++r)
    op[r] = O + (bbase + (size_t)(c0 + q * 4 + r) * CHUNK) * 256 + g64 * 64 + 2 * hf * 16 + l15;

  h2 up0 = uload(-WARM, 0), up1 = uload(-WARM, 1), up2 = uload(-WARM, 2), up3 = uload(-WARM, 3);
  __syncthreads();  // one full drain: zero-init + frag loads

  int cb = 0;
#pragma unroll 1
  for (int g = 0; g <= STEPS; ++g) {
    const int t = g - WARM;  // computes S_t (g<STEPS); emits O_{t-1} (t>=1)
    // prefetch next step's U fragments (overlaps this step's MFMA; never drained)
    h2 un0 = uload(t + 1, 0), un1 = uload(t + 1, 1), un2 = uload(t + 1, 2), un3 = uload(t + 1, 3);
    if (g < STEPS) {
      f32x4 acc[2];
#pragma unroll
      for (int ctl = 0; ctl < 2; ++ctl) {
        acc[ctl][0] = (float)up0[ctl]; acc[ctl][1] = (float)up1[ctl];
        acc[ctl][2] = (float)up2[ctl]; acc[ctl][3] = (float)up3[ctl];
      }
      if (t >= 1) {
        f32x4 acc2[2] = {};
#pragma unroll
        for (int kb = 0; kb < 8; ++kb) {
          h8 af = *(const h8*)&st[cb][l15][kb * 32 + q * 8];
#pragma unroll
          for (int ctl = 0; ctl < 2; ++ctl)
            acc[ctl] = __builtin_amdgcn_mfma_f32_16x16x32_f16(af, bf[ctl][kb], acc[ctl], 0, 0, 0);
#pragma unroll
          for (int ctl = 0; ctl < 2; ++ctl)
            acc2[ctl] = __builtin_amdgcn_mfma_f32_16x16x32_f16(af, cf[ctl][kb], acc2[ctl], 0, 0, 0);
        }
#pragma unroll
        for (int ctl = 0; ctl < 2; ++ctl)
#pragma unroll
          for (int r = 0; r < 4; ++r)
            st[cb ^ 1][q * 4 + r][g64 * 64 + (2 * hf + ctl) * 16 + l15] = (_Float16)acc[ctl][r];
#pragma unroll
        for (int r = 0; r < 4; ++r) {
          op[r][0] = acc2[0][r];
          op[r][16] = acc2[1][r];
          op[r] += 256;
        }
      } else {
#pragma unroll
        for (int kb = 0; kb < 8; ++kb) {
          h8 af = *(const h8*)&st[cb][l15][kb * 32 + q * 8];
#pragma unroll
          for (int ctl = 0; ctl < 2; ++ctl)
            acc[ctl] = __builtin_amdgcn_mfma_f32_16x16x32_f16(af, bf[ctl][kb], acc[ctl], 0, 0, 0);
        }
#pragma unroll
        for (int ctl = 0; ctl < 2; ++ctl)
#pragma unroll
          for (int r = 0; r < 4; ++r)
            st[cb ^ 1][q * 4 + r][g64 * 64 + (2 * hf + ctl) * 16 + l15] = (_Float16)acc[ctl][r];
      }
    } else {  // g == STEPS: final O_{CHUNK-1} only
      f32x4 acc2[2] = {};
#pragma unroll
      for (int kb = 0; kb < 8; ++kb) {
        h8 af = *(const h8*)&st[cb][l15][kb * 32 + q * 8];
#pragma unroll
        for (int ctl = 0; ctl < 2; ++ctl)
          acc2[ctl] = __builtin_amdgcn_mfma_f32_16x16x32_f16(af, cf[ctl][kb], acc2[ctl], 0, 0, 0);
      }
#pragma unroll
      for (int r = 0; r < 4; ++r) {
        op[r][0] = acc2[0][r];
        op[r][16] = acc2[1][r];
      }
    }
    // cross-wave hazard is LDS-only (st dbuf): wait LDS, barrier — NO vmem drain
    asm volatile("s_waitcnt lgkmcnt(0)" ::: "memory");
    __builtin_amdgcn_s_barrier();
    asm volatile("" ::: "memory");
    up0 = un0; up1 = un1; up2 = un2; up3 = un3;
    cb ^= 1;
  }
}

extern "C" void kernel_launch(void* const* d_in, const int* in_sizes, int n_in,
                              void* d_out, int out_size, void* d_ws, size_t ws_size,
                              hipStream_t stream) {
  const float* x = (const float*)d_in[0];
  const float* A = (const float*)d_in[1];
  const float* B = (const float*)d_in[2];
  const float* C = (const float*)d_in[3];

  char* ws = (char*)d_ws;
  _Float16* U = (_Float16*)ws;                              // 33.5 MB (swizzled)
  _Float16* AhT = (_Float16*)(ws + 33554432);               // 128 KB
  _Float16* Ch = (_Float16*)(ws + 33554432 + 131072);       // 128 KB
  _Float16* Zph = (_Float16*)(ws + 33554432 + 262144);      // 1 KB zeros
  _Float16* Bpack = (_Float16*)(ws + 33554432 + 393216);    // 128 KB frag-major
  float* out = (float*)d_out;

  hipLaunchKernelGGL(k_pack, dim3(256), dim3(256), 0, stream, A, B, C, AhT, Ch, Zph,
                     Bpack);
  hipLaunchKernelGGL(k_gemm_u, dim3(2048), dim3(256), 0, stream, x, Bpack, U);
  hipLaunchKernelGGL(k_scan, dim3(256), dim3(512), 0, stream, U, AhT, Ch, Zph, out);
}